// Round 9
// baseline (501.525 us; speedup 1.0000x reference)
//
#include <hip/hip_runtime.h>

typedef __attribute__((ext_vector_type(8))) short  s16x8;
typedef __attribute__((ext_vector_type(8))) unsigned short u16x8;
typedef __attribute__((ext_vector_type(4))) float  f32x4;

constexpr float BN_EPS = 1e-5f;
#define DEV_INLINE __device__ __forceinline__

DEV_INLINE ushort f2bf(float f) {
  unsigned int u = __float_as_uint(f);
  return (ushort)((u + 0x7FFFu + ((u >> 16) & 1u)) >> 16);
}
DEV_INLINE float bf2f(ushort b) { return __uint_as_float(((unsigned int)b) << 16); }

DEV_INLINE unsigned int cvtpk(float a, float b) {
  unsigned int r;
  asm volatile("v_cvt_pk_bf16_f32 %0, %1, %2" : "=v"(r) : "v"(a), "v"(b));
  return r;
}

DEV_INLINE f32x4 mfma16(s16x8 a, s16x8 b, f32x4 c) {
  return __builtin_amdgcn_mfma_f32_16x16x32_bf16(a, b, c, 0, 0, 0);
}

// packed B-fragment index decode: r in [0,1024) -> (k, col16)
DEV_INLINE void decode_frag(int r, int& k, int& c16) {
  const int ks = r >> 9;
  const int l = (r >> 3) & 63;
  const int j = r & 7;
  k = ks * 32 + ((l >> 4) << 3) + j;
  c16 = l & 15;
}

// ---- pack W1|Ws (20 ct), Wk (9x4 ct), W3 (16 ct); zero stats region --------
__global__ void kPackW(const float* __restrict__ W1, const float* __restrict__ Ws,
                       const float* __restrict__ Wk, const float* __restrict__ W3,
                       ushort* __restrict__ WP1S, ushort* __restrict__ WPk,
                       ushort* __restrict__ WP3, float* __restrict__ statz) {
  int e = blockIdx.x * 256 + threadIdx.x;  // 73728 total
  if (e < 1280) statz[e] = 0.f;
  if (e < 20480) {
    int ct = e >> 10, r = e & 1023, k, c16;
    decode_frag(r, k, c16);
    float w = (ct < 4) ? W1[k * 64 + ct * 16 + c16] : Ws[k * 256 + (ct - 4) * 16 + c16];
    WP1S[e] = f2bf(w);
  } else if (e < 57344) {
    int e2 = e - 20480;
    int tap = e2 >> 12, r2 = e2 & 4095;
    int ct = r2 >> 10, k, c16;
    decode_frag(r2 & 1023, k, c16);
    WPk[e2] = f2bf(Wk[tap * 4096 + k * 64 + ct * 16 + c16]);
  } else {
    int e3 = e - 57344;
    int ct = e3 >> 10, k, c16;
    decode_frag(e3 & 1023, k, c16);
    WP3[e3] = f2bf(W3[k * 256 + ct * 16 + c16]);
  }
}

// per-block BN finalize helper: channel j from global sums -> a,c
DEV_INLINE void bnFin(const float* sum, const float* sq, const float* g,
                      const float* b, float invN, int j, float* a_lds, float* c_lds) {
  float m = sum[j] * invN;
  float v = fmaxf(sq[j] * invN - m * m, 0.f);
  float al = g[j] * rsqrtf(v + BN_EPS);
  a_lds[j] = al;
  c_lds[j] = fmaf(-m, al, b[j]);
}

// ---- K1: colsum/colsq of X@[W1|Ws] (320 cols); writes Xb; by-ct waves ------
__global__ __launch_bounds__(256) void kStatsXW(const float* __restrict__ X,
                                                const ushort* __restrict__ WP,
                                                ushort* __restrict__ Xb,
                                                float* __restrict__ gsum,
                                                float* __restrict__ gsq,
                                                int N, int ntiles) {
  __shared__ ushort At[64 * 64];
  const int tid = threadIdx.x;
  const int l = tid & 63, w = tid >> 6;
  const int kb = (l >> 4) << 4;
  const int r = tid >> 2, q = tid & 3;
  const int sww = (r & 7) << 4;
  const u16x8* wp = (const u16x8*)WP;
  // wave w owns cts [5w, 5w+5): weights resident in regs
  s16x8 wgt[5][2];
#pragma unroll
  for (int i = 0; i < 5; ++i)
#pragma unroll
    for (int j = 0; j < 2; ++j) wgt[i][j] = (s16x8)wp[((w * 5 + i) * 2 + j) * 64 + l];
  float sA[5] = {0.f, 0.f, 0.f, 0.f, 0.f}, qA[5] = {0.f, 0.f, 0.f, 0.f, 0.f};
  for (int t = blockIdx.x; t < ntiles; t += gridDim.x) {
    const int row0 = t * 64;
    const int grow = row0 + r;
    u16x8 lo = {0, 0, 0, 0, 0, 0, 0, 0}, hi = {0, 0, 0, 0, 0, 0, 0, 0};
    if (grow < N) {
      const float4* xp = reinterpret_cast<const float4*>(&X[(size_t)grow * 64 + q * 16]);
      float4 x0 = xp[0], x1 = xp[1], x2 = xp[2], x3 = xp[3];
      union { u16x8 v; unsigned int d[4]; } ul, uh;
      ul.d[0] = cvtpk(x0.x, x0.y); ul.d[1] = cvtpk(x0.z, x0.w);
      ul.d[2] = cvtpk(x1.x, x1.y); ul.d[3] = cvtpk(x1.z, x1.w);
      uh.d[0] = cvtpk(x2.x, x2.y); uh.d[1] = cvtpk(x2.z, x2.w);
      uh.d[2] = cvtpk(x3.x, x3.y); uh.d[3] = cvtpk(x3.z, x3.w);
      lo = ul.v; hi = uh.v;
      *(u16x8*)&Xb[(size_t)grow * 64 + q * 16] = lo;
      *(u16x8*)&Xb[(size_t)grow * 64 + q * 16 + 8] = hi;
    }
    __syncthreads();  // prev tile's At reads done
    char* wb = (char*)At + r * 128;
    *(u16x8*)(wb + ((q * 32) ^ sww)) = lo;
    *(u16x8*)(wb + ((q * 32 + 16) ^ sww)) = hi;
    __syncthreads();
#pragma unroll
    for (int rb = 0; rb < 4; ++rb) {
      const int rowa = rb * 16 + (l & 15);
      const char* ab = (const char*)At + rowa * 128;
      const int swa = (rowa & 7) << 4;
      const s16x8 a0 = *(const s16x8*)(ab + (kb ^ swa));
      const s16x8 a1 = *(const s16x8*)(ab + ((64 + kb) ^ swa));
#pragma unroll
      for (int i = 0; i < 5; ++i) {
        f32x4 acc = {0.f, 0.f, 0.f, 0.f};
        acc = mfma16(a0, wgt[i][0], acc);
        acc = mfma16(a1, wgt[i][1], acc);
        sA[i] += acc[0] + acc[1] + acc[2] + acc[3];
        qA[i] += acc[0] * acc[0] + acc[1] * acc[1] + acc[2] * acc[2] + acc[3] * acc[3];
      }
    }
  }
#pragma unroll
  for (int i = 0; i < 5; ++i) {
    float sp = sA[i], qp = qA[i];
    sp += __shfl_xor(sp, 16); sp += __shfl_xor(sp, 32);
    qp += __shfl_xor(qp, 16); qp += __shfl_xor(qp, 32);
    if (l < 16) {
      atomicAdd(&gsum[(w * 5 + i) * 16 + l], sp);
      atomicAdd(&gsq[(w * 5 + i) * 16 + l], qp);
    }
  }
}

// ---- K2: h1 = relu(a1*(Xb@W1)+c1) -> bf16; by-ct (wave=ct); multi-tile -----
__global__ __launch_bounds__(256) void kGemm1(const ushort* __restrict__ Xb,
                                              const ushort* __restrict__ WP,
                                              const float* __restrict__ sum1,
                                              const float* __restrict__ sq1,
                                              const float* __restrict__ g1,
                                              const float* __restrict__ b1,
                                              float invN, ushort* __restrict__ H1,
                                              int N, int ntiles) {
  __shared__ ushort At[64 * 64];
  __shared__ float a1s[64], c1s[64];
  const int tid = threadIdx.x;
  if (tid < 64) bnFin(sum1, sq1, g1, b1, invN, tid, a1s, c1s);
  const int l = tid & 63, w = tid >> 6;
  const int kb = (l >> 4) << 4;
  const int r = tid >> 2, q = tid & 3;
  const int sww = (r & 7) << 4;
  const u16x8* wp = (const u16x8*)WP;
  const s16x8 wg0 = (s16x8)wp[(w * 2 + 0) * 64 + l];
  const s16x8 wg1 = (s16x8)wp[(w * 2 + 1) * 64 + l];
  const int col = w * 16 + (l & 15);
  for (int t = blockIdx.x; t < ntiles; t += gridDim.x) {
    const int row0 = t * 64;
    const int grow = row0 + r;
    u16x8 lo = {0, 0, 0, 0, 0, 0, 0, 0}, hi = {0, 0, 0, 0, 0, 0, 0, 0};
    if (grow < N) {
      const u16x8* hp = (const u16x8*)&Xb[(size_t)grow * 64 + q * 16];
      lo = hp[0];
      hi = hp[1];
    }
    __syncthreads();
    char* wb = (char*)At + r * 128;
    *(u16x8*)(wb + ((q * 32) ^ sww)) = lo;
    *(u16x8*)(wb + ((q * 32 + 16) ^ sww)) = hi;
    __syncthreads();
    const float aj = a1s[col], cj = c1s[col];
#pragma unroll
    for (int rb = 0; rb < 4; ++rb) {
      const int rowa = rb * 16 + (l & 15);
      const char* ab = (const char*)At + rowa * 128;
      const int swa = (rowa & 7) << 4;
      const s16x8 a0 = *(const s16x8*)(ab + (kb ^ swa));
      const s16x8 a1 = *(const s16x8*)(ab + ((64 + kb) ^ swa));
      f32x4 acc = {0.f, 0.f, 0.f, 0.f};
      acc = mfma16(a0, wg0, acc);
      acc = mfma16(a1, wg1, acc);
#pragma unroll
      for (int reg = 0; reg < 4; ++reg) {
        const int gr = row0 + rb * 16 + ((l >> 4) << 2) + reg;
        if (gr < N)
          H1[(size_t)gr * 64 + col] =
              (ushort)cvtpk(fmaxf(fmaf(acc[reg], aj, cj), 0.f), 0.f);
      }
    }
  }
}

// ---- K3: Y2 = sum_k gather_k(h1) @ Wk[k] + BN2 stats -----------------------
// ping-pong register prefetch: gather t+1 issues AFTER staging barrier, flies
// during tile t's MFMA phase; reg stats flushed once per block.
__global__ __launch_bounds__(256, 2) void kConv(const ushort* __restrict__ H1,
                                                const int* __restrict__ nbr,
                                                const ushort* __restrict__ WPk,
                                                ushort* __restrict__ Y2b,
                                                float* __restrict__ gsum,
                                                float* __restrict__ gsq,
                                                int N, int ntiles, int tpb) {
  __shared__ ushort At[9][64 * 64];
  __shared__ float lsum[64], lsq[64];
  const int tid = threadIdx.x;
  if (tid < 64) { lsum[tid] = 0.f; lsq[tid] = 0.f; }
  const int l = tid & 63, w = tid >> 6;
  const int rowb = w * 16 + (l & 15);
  const int swr = (rowb & 7) << 4;
  const int kb = (l >> 4) << 4;
  const int r = tid >> 2, q = tid & 3;
  const int sww = (r & 7) << 4;
  const u16x8* wp = (const u16x8*)WPk;
  const int t0 = blockIdx.x * tpb;
  const int t1 = (t0 + tpb < ntiles) ? (t0 + tpb) : ntiles;
  float sAcc[4] = {0.f, 0.f, 0.f, 0.f}, qAcc[4] = {0.f, 0.f, 0.f, 0.f};

  u16x8 lA[9], hA[9], lB[9], hB[9];

  auto gather = [&](u16x8 (&glo)[9], u16x8 (&ghi)[9], int t) {
    const int grow = t * 64 + r;
#pragma unroll
    for (int k = 0; k < 9; ++k) {
      u16x8 z = {0, 0, 0, 0, 0, 0, 0, 0};
      glo[k] = z;
      ghi[k] = z;
    }
    if (grow < N) {
#pragma unroll
      for (int k = 0; k < 9; ++k) {
        const int src = nbr[(size_t)grow * 9 + k];
        if (src >= 0) {
          const u16x8* hp = (const u16x8*)&H1[(size_t)src * 64 + q * 16];
          glo[k] = hp[0];
          ghi[k] = hp[1];
        }
      }
    }
  };
  auto stageRegs = [&](u16x8 (&glo)[9], u16x8 (&ghi)[9]) {
#pragma unroll
    for (int k = 0; k < 9; ++k) {
      char* wb = (char*)At[k] + r * 128;
      *(u16x8*)(wb + ((q * 32) ^ sww)) = glo[k];
      *(u16x8*)(wb + ((q * 32 + 16) ^ sww)) = ghi[k];
    }
  };
  auto mfmaTile = [&](int t) {
    const int row0 = t * 64;
    f32x4 acc[4];
#pragma unroll
    for (int ct = 0; ct < 4; ++ct) acc[ct] = {0.f, 0.f, 0.f, 0.f};
#pragma unroll
    for (int k = 0; k < 9; ++k) {
      const char* ab = (const char*)At[k] + rowb * 128;
      const s16x8 a0 = *(const s16x8*)(ab + (kb ^ swr));
      const s16x8 a1 = *(const s16x8*)(ab + ((64 + kb) ^ swr));
#pragma unroll
      for (int ct = 0; ct < 4; ++ct) {
        s16x8 b0 = (s16x8)wp[(size_t)((k * 4 + ct) * 2 + 0) * 64 + l];
        s16x8 b1 = (s16x8)wp[(size_t)((k * 4 + ct) * 2 + 1) * 64 + l];
        acc[ct] = mfma16(a0, b0, acc[ct]);
        acc[ct] = mfma16(a1, b1, acc[ct]);
      }
    }
#pragma unroll
    for (int ct = 0; ct < 4; ++ct) {
      const f32x4 v = acc[ct];
      const int col = ct * 16 + (l & 15);
#pragma unroll
      for (int reg = 0; reg < 4; ++reg) {
        const int grow = row0 + w * 16 + ((l >> 4) << 2) + reg;
        if (grow < N) Y2b[(size_t)grow * 64 + col] = (ushort)cvtpk(v[reg], v[reg]);
      }
      sAcc[ct] += v[0] + v[1] + v[2] + v[3];
      qAcc[ct] += v[0] * v[0] + v[1] * v[1] + v[2] * v[2] + v[3] * v[3];
    }
  };

  if (t0 < t1) gather(lA, hA, t0);
  int t = t0;
  while (t < t1) {
    stageRegs(lA, hA);
    __syncthreads();                       // At staged (no gathers outstanding)
    if (t + 1 < t1) gather(lB, hB, t + 1); // flies under MFMA phase
    mfmaTile(t);
    __syncthreads();                       // reads done; gathers drained (were done)
    ++t;
    if (t >= t1) break;
    stageRegs(lB, hB);
    __syncthreads();
    if (t + 1 < t1) gather(lA, hA, t + 1);
    mfmaTile(t);
    __syncthreads();
    ++t;
  }
  __syncthreads();  // lsum init visible (covers empty-range blocks)
#pragma unroll
  for (int ct = 0; ct < 4; ++ct) {
    float sp = sAcc[ct], qp = qAcc[ct];
    sp += __shfl_xor(sp, 16); sp += __shfl_xor(sp, 32);
    qp += __shfl_xor(qp, 16); qp += __shfl_xor(qp, 32);
    if (l < 16) {
      atomicAdd(&lsum[ct * 16 + l], sp);
      atomicAdd(&lsq[ct * 16 + l], qp);
    }
  }
  __syncthreads();
  if (tid < 64) {
    atomicAdd(&gsum[tid], lsum[tid]);
    atomicAdd(&gsq[tid], lsq[tid]);
  }
}

// ---- K4: BN3 stats of h2@W3 (h2 in-register); by-ct waves; multi-tile ------
__global__ __launch_bounds__(256) void kH2S3(const ushort* __restrict__ Y2b,
                                             const float* __restrict__ sum2,
                                             const float* __restrict__ sq2,
                                             const float* __restrict__ g2,
                                             const float* __restrict__ b2,
                                             float invN,
                                             const ushort* __restrict__ WP3,
                                             float* __restrict__ gsum,
                                             float* __restrict__ gsq,
                                             int N, int ntiles) {
  __shared__ ushort At[64 * 64];
  __shared__ float a2s[64], c2s[64];
  const int tid = threadIdx.x;
  if (tid < 64) bnFin(sum2, sq2, g2, b2, invN, tid, a2s, c2s);
  const int l = tid & 63, w = tid >> 6;
  const int kb = (l >> 4) << 4;
  const int r = tid >> 2, q = tid & 3;
  const int sww = (r & 7) << 4;
  const u16x8* wp = (const u16x8*)WP3;
  s16x8 wgt[4][2];
#pragma unroll
  for (int i = 0; i < 4; ++i)
#pragma unroll
    for (int j = 0; j < 2; ++j) wgt[i][j] = (s16x8)wp[((w * 4 + i) * 2 + j) * 64 + l];
  float sA[4] = {0.f, 0.f, 0.f, 0.f}, qA[4] = {0.f, 0.f, 0.f, 0.f};
  __syncthreads();  // a2s ready
  for (int t = blockIdx.x; t < ntiles; t += gridDim.x) {
    const int row0 = t * 64;
    const int grow = row0 + r;
    u16x8 lo = {0, 0, 0, 0, 0, 0, 0, 0}, hi = {0, 0, 0, 0, 0, 0, 0, 0};
    if (grow < N) {
      const u16x8* yp = (const u16x8*)&Y2b[(size_t)grow * 64 + q * 16];
      u16x8 ylo = yp[0], yhi = yp[1];
      const int cb = q * 16;
      float f[8], g[8];
#pragma unroll
      for (int i = 0; i < 8; ++i) {
        f[i] = fmaxf(fmaf(bf2f(ylo[i]), a2s[cb + i], c2s[cb + i]), 0.f);
        g[i] = fmaxf(fmaf(bf2f(yhi[i]), a2s[cb + 8 + i], c2s[cb + 8 + i]), 0.f);
      }
      union { u16x8 v; unsigned int d[4]; } ul, uh;
#pragma unroll
      for (int i = 0; i < 4; ++i) {
        ul.d[i] = cvtpk(f[2 * i], f[2 * i + 1]);
        uh.d[i] = cvtpk(g[2 * i], g[2 * i + 1]);
      }
      lo = ul.v; hi = uh.v;
    }
    __syncthreads();  // prev reads done
    char* wb = (char*)At + r * 128;
    *(u16x8*)(wb + ((q * 32) ^ sww)) = lo;
    *(u16x8*)(wb + ((q * 32 + 16) ^ sww)) = hi;
    __syncthreads();
#pragma unroll
    for (int rb = 0; rb < 4; ++rb) {
      const int rowa = rb * 16 + (l & 15);
      const char* ab = (const char*)At + rowa * 128;
      const int swa = (rowa & 7) << 4;
      const s16x8 a0 = *(const s16x8*)(ab + (kb ^ swa));
      const s16x8 a1 = *(const s16x8*)(ab + ((64 + kb) ^ swa));
#pragma unroll
      for (int i = 0; i < 4; ++i) {
        f32x4 acc = {0.f, 0.f, 0.f, 0.f};
        acc = mfma16(a0, wgt[i][0], acc);
        acc = mfma16(a1, wgt[i][1], acc);
        sA[i] += acc[0] + acc[1] + acc[2] + acc[3];
        qA[i] += acc[0] * acc[0] + acc[1] * acc[1] + acc[2] * acc[2] + acc[3] * acc[3];
      }
    }
  }
#pragma unroll
  for (int i = 0; i < 4; ++i) {
    float sp = sA[i], qp = qA[i];
    sp += __shfl_xor(sp, 16); sp += __shfl_xor(sp, 32);
    qp += __shfl_xor(qp, 16); qp += __shfl_xor(qp, 32);
    if (l < 16) {
      atomicAdd(&gsum[(w * 4 + i) * 16 + l], sp);
      atomicAdd(&gsq[(w * 4 + i) * 16 + l], qp);
    }
  }
}

// ---- K5: out = relu(a3*(h2@W3) + aS*(Xb@Ws) + c3+cS); by-ct; multi-tile ----
__global__ __launch_bounds__(256, 2) void kFinal(
    const ushort* __restrict__ Y2b, const ushort* __restrict__ Xb,
    const ushort* __restrict__ WP3, const ushort* __restrict__ WP1S,
    const float* __restrict__ sum2, const float* __restrict__ sq2,
    const float* __restrict__ g2, const float* __restrict__ b2,
    const float* __restrict__ sum3, const float* __restrict__ sq3,
    const float* __restrict__ g3, const float* __restrict__ b3,
    const float* __restrict__ sumS, const float* __restrict__ sqS,
    const float* __restrict__ gs, const float* __restrict__ bs,
    float invN, float* __restrict__ OUT, int N, int ntiles) {
  __shared__ ushort Ah[64 * 64];
  __shared__ ushort Ax[64 * 64];
  __shared__ float a2s[64], c2s[64];
  __shared__ float a3s[256], c3s[256], aSs[256], cSs[256];
  const int tid = threadIdx.x;
  if (tid < 64) bnFin(sum2, sq2, g2, b2, invN, tid, a2s, c2s);
  bnFin(sum3, sq3, g3, b3, invN, tid, a3s, c3s);
  bnFin(sumS, sqS, gs, bs, invN, tid, aSs, cSs);
  const int l = tid & 63, w = tid >> 6;
  const int kb = (l >> 4) << 4;
  const int r = tid >> 2, q = tid & 3;
  const int sww = (r & 7) << 4;
  const u16x8* wp3 = (const u16x8*)WP3;
  const u16x8* wps = (const u16x8*)WP1S + 8 * 64;  // skip W1's 4 ct
  s16x8 w3[4][2], wsv[4][2];
#pragma unroll
  for (int i = 0; i < 4; ++i)
#pragma unroll
    for (int j = 0; j < 2; ++j) {
      w3[i][j]  = (s16x8)wp3[((w * 4 + i) * 2 + j) * 64 + l];
      wsv[i][j] = (s16x8)wps[((w * 4 + i) * 2 + j) * 64 + l];
    }
  __syncthreads();  // BN LDS ready
  for (int t = blockIdx.x; t < ntiles; t += gridDim.x) {
    const int row0 = t * 64;
    const int grow = row0 + r;
    u16x8 xlo = {0, 0, 0, 0, 0, 0, 0, 0}, xhi = {0, 0, 0, 0, 0, 0, 0, 0};
    u16x8 hlo = {0, 0, 0, 0, 0, 0, 0, 0}, hhi = {0, 0, 0, 0, 0, 0, 0, 0};
    if (grow < N) {
      const u16x8* hp = (const u16x8*)&Xb[(size_t)grow * 64 + q * 16];
      xlo = hp[0];
      xhi = hp[1];
      const u16x8* yp = (const u16x8*)&Y2b[(size_t)grow * 64 + q * 16];
      u16x8 ylo = yp[0], yhi = yp[1];
      const int cb = q * 16;
      float f[8], g[8];
#pragma unroll
      for (int i = 0; i < 8; ++i) {
        f[i] = fmaxf(fmaf(bf2f(ylo[i]), a2s[cb + i], c2s[cb + i]), 0.f);
        g[i] = fmaxf(fmaf(bf2f(yhi[i]), a2s[cb + 8 + i], c2s[cb + 8 + i]), 0.f);
      }
      union { u16x8 v; unsigned int d[4]; } ul, uh;
#pragma unroll
      for (int i = 0; i < 4; ++i) {
        ul.d[i] = cvtpk(f[2 * i], f[2 * i + 1]);
        uh.d[i] = cvtpk(g[2 * i], g[2 * i + 1]);
      }
      hlo = ul.v; hhi = uh.v;
    }
    __syncthreads();  // prev reads done
    {
      char* bh = (char*)Ah + r * 128;
      char* bx = (char*)Ax + r * 128;
      *(u16x8*)(bh + ((q * 32) ^ sww)) = hlo;
      *(u16x8*)(bh + ((q * 32 + 16) ^ sww)) = hhi;
      *(u16x8*)(bx + ((q * 32) ^ sww)) = xlo;
      *(u16x8*)(bx + ((q * 32 + 16) ^ sww)) = xhi;
    }
    __syncthreads();
    // hoist A fragments (16 ds_reads), then 64 MFMAs with zero LDS
    s16x8 ah0[4], ah1[4], ax0[4], ax1[4];
#pragma unroll
    for (int rb = 0; rb < 4; ++rb) {
      const int rowa = rb * 16 + (l & 15);
      const int swa = (rowa & 7) << 4;
      const char* hb = (const char*)Ah + rowa * 128;
      const char* xb2 = (const char*)Ax + rowa * 128;
      ah0[rb] = *(const s16x8*)(hb + (kb ^ swa));
      ah1[rb] = *(const s16x8*)(hb + ((64 + kb) ^ swa));
      ax0[rb] = *(const s16x8*)(xb2 + (kb ^ swa));
      ax1[rb] = *(const s16x8*)(xb2 + ((64 + kb) ^ swa));
    }
#pragma unroll
    for (int i = 0; i < 4; ++i) {
      const int col = (w * 4 + i) * 16 + (l & 15);
      const float a3j = a3s[col], aSj = aSs[col];
      const float ccj = c3s[col] + cSs[col];
#pragma unroll
      for (int rb = 0; rb < 4; ++rb) {
        f32x4 acc3 = {0.f, 0.f, 0.f, 0.f};
        acc3 = mfma16(ah0[rb], w3[i][0], acc3);
        acc3 = mfma16(ah1[rb], w3[i][1], acc3);
        f32x4 accS = {0.f, 0.f, 0.f, 0.f};
        accS = mfma16(ax0[rb], wsv[i][0], accS);
        accS = mfma16(ax1[rb], wsv[i][1], accS);
#pragma unroll
        for (int reg = 0; reg < 4; ++reg) {
          const int gr = row0 + rb * 16 + ((l >> 4) << 2) + reg;
          if (gr < N) {
            const float ov = fmaxf(fmaf(acc3[reg], a3j, fmaf(accS[reg], aSj, ccj)), 0.f);
            __builtin_nontemporal_store(ov, &OUT[(size_t)gr * 256 + col]);
          }
        }
      }
    }
  }
}

extern "C" void kernel_launch(void* const* d_in, const int* in_sizes, int n_in,
                              void* d_out, int out_size, void* d_ws, size_t ws_size,
                              hipStream_t stream) {
  const float* X  = (const float*)d_in[0];
  const int*   nbr = (const int*)d_in[1];
  const float* W1 = (const float*)d_in[2];
  const float* g1 = (const float*)d_in[3];
  const float* b1 = (const float*)d_in[4];
  const float* Wk = (const float*)d_in[5];
  const float* g2 = (const float*)d_in[6];
  const float* b2 = (const float*)d_in[7];
  const float* W3 = (const float*)d_in[8];
  const float* g3 = (const float*)d_in[9];
  const float* b3 = (const float*)d_in[10];
  const float* Ws = (const float*)d_in[11];
  const float* gs = (const float*)d_in[12];
  const float* bs = (const float*)d_in[13];
  float* out = (float*)d_out;
  float* ws  = (float*)d_ws;

  const int N = in_sizes[0] / 64;
  const float invN = 1.f / (float)N;
  const int ntiles = (N + 63) / 64;

  // ws layout (float offsets)
  float* sum1S = ws + 0;     // [320]
  float* sq1S  = ws + 320;   // [320]
  float* sum2  = ws + 640;   // [64]
  float* sq2   = ws + 704;   // [64]
  float* sum3  = ws + 768;   // [256]
  float* sq3   = ws + 1024;  // [256]
  ushort* WP1S = (ushort*)(ws + 1280);   // 20480 bf16
  ushort* WPkP = (ushort*)(ws + 11520);  // 36864 bf16
  ushort* WP3P = (ushort*)(ws + 29952);  // 16384 bf16
  ushort* Xb   = (ushort*)(ws + 38144);                      // N*64 bf16
  ushort* Y2b  = (ushort*)(ws + 38144 + (size_t)N * 32);     // N*64 bf16
  ushort* H1b  = (ushort*)(ws + 38144 + (size_t)N * 64);     // N*64 bf16

  const int convGrid = 512;
  const int tpb = (ntiles + convGrid - 1) / convGrid;

  kPackW<<<288, 256, 0, stream>>>(W1, Ws, Wk, W3, WP1S, WPkP, WP3P, ws);
  kStatsXW<<<508, 256, 0, stream>>>(X, WP1S, Xb, sum1S, sq1S, N, ntiles);
  kGemm1<<<508, 256, 0, stream>>>(Xb, WP1S, sum1S, sq1S, g1, b1, invN, H1b, N, ntiles);
  kConv<<<convGrid, 256, 0, stream>>>(H1b, nbr, WPkP, Y2b, sum2, sq2, N, ntiles, tpb);
  kH2S3<<<508, 256, 0, stream>>>(Y2b, sum2, sq2, g2, b2, invN, WP3P, sum3, sq3, N, ntiles);
  kFinal<<<512, 256, 0, stream>>>(Y2b, Xb, WP3P, WP1S, sum2, sq2, g2, b2,
                                  sum3, sq3, g3, b3, sum1S + 64, sq1S + 64,
                                  gs, bs, invN, out, N, ntiles);
}

// Round 10
// 222.494 us; speedup vs baseline: 2.2541x; 2.2541x over previous
//
#include <hip/hip_runtime.h>

typedef __attribute__((ext_vector_type(8))) short  s16x8;
typedef __attribute__((ext_vector_type(8))) unsigned short u16x8;
typedef __attribute__((ext_vector_type(4))) float  f32x4;

constexpr float BN_EPS = 1e-5f;
#define DEV_INLINE __device__ __forceinline__

DEV_INLINE ushort f2bf(float f) {
  unsigned int u = __float_as_uint(f);
  return (ushort)((u + 0x7FFFu + ((u >> 16) & 1u)) >> 16);
}
DEV_INLINE float bf2f(ushort b) { return __uint_as_float(((unsigned int)b) << 16); }

DEV_INLINE unsigned int cvtpk(float a, float b) {
  unsigned int r;
  asm volatile("v_cvt_pk_bf16_f32 %0, %1, %2" : "=v"(r) : "v"(a), "v"(b));
  return r;
}

DEV_INLINE f32x4 mfma16(s16x8 a, s16x8 b, f32x4 c) {
  return __builtin_amdgcn_mfma_f32_16x16x32_bf16(a, b, c, 0, 0, 0);
}

// packed B-fragment index decode: r in [0,1024) -> (k, col16)
DEV_INLINE void decode_frag(int r, int& k, int& c16) {
  const int ks = r >> 9;
  const int l = (r >> 3) & 63;
  const int j = r & 7;
  k = ks * 32 + ((l >> 4) << 3) + j;
  c16 = l & 15;
}

// ---- pack W1|Ws (20 ct), Wk (9x4 ct), W3 (16 ct); zero stats region --------
__global__ void kPackW(const float* __restrict__ W1, const float* __restrict__ Ws,
                       const float* __restrict__ Wk, const float* __restrict__ W3,
                       ushort* __restrict__ WP1S, ushort* __restrict__ WPk,
                       ushort* __restrict__ WP3, float* __restrict__ statz) {
  int e = blockIdx.x * 256 + threadIdx.x;  // 73728 total
  if (e < 1280) statz[e] = 0.f;
  if (e < 20480) {
    int ct = e >> 10, r = e & 1023, k, c16;
    decode_frag(r, k, c16);
    float w = (ct < 4) ? W1[k * 64 + ct * 16 + c16] : Ws[k * 256 + (ct - 4) * 16 + c16];
    WP1S[e] = f2bf(w);
  } else if (e < 57344) {
    int e2 = e - 20480;
    int tap = e2 >> 12, r2 = e2 & 4095;
    int ct = r2 >> 10, k, c16;
    decode_frag(r2 & 1023, k, c16);
    WPk[e2] = f2bf(Wk[tap * 4096 + k * 64 + ct * 16 + c16]);
  } else {
    int e3 = e - 57344;
    int ct = e3 >> 10, k, c16;
    decode_frag(e3 & 1023, k, c16);
    WP3[e3] = f2bf(W3[k * 256 + ct * 16 + c16]);
  }
}

// per-block BN finalize helper: channel j from global sums -> a,c
DEV_INLINE void bnFin(const float* sum, const float* sq, const float* g,
                      const float* b, float invN, int j, float* a_lds, float* c_lds) {
  float m = sum[j] * invN;
  float v = fmaxf(sq[j] * invN - m * m, 0.f);
  float al = g[j] * rsqrtf(v + BN_EPS);
  a_lds[j] = al;
  c_lds[j] = fmaf(-m, al, b[j]);
}

// ---- K1: colsum/colsq of X@[W1|Ws] (320 cols); writes Xb; by-ct waves ------
__global__ __launch_bounds__(256) void kStatsXW(const float* __restrict__ X,
                                                const ushort* __restrict__ WP,
                                                ushort* __restrict__ Xb,
                                                float* __restrict__ gsum,
                                                float* __restrict__ gsq,
                                                int N, int ntiles) {
  __shared__ ushort At[64 * 64];
  const int tid = threadIdx.x;
  const int l = tid & 63, w = tid >> 6;
  const int kb = (l >> 4) << 4;
  const int r = tid >> 2, q = tid & 3;
  const int sww = (r & 7) << 4;
  const u16x8* wp = (const u16x8*)WP;
  // wave w owns cts [5w, 5w+5): weights resident in regs
  s16x8 wgt[5][2];
#pragma unroll
  for (int i = 0; i < 5; ++i)
#pragma unroll
    for (int j = 0; j < 2; ++j) wgt[i][j] = (s16x8)wp[((w * 5 + i) * 2 + j) * 64 + l];
  float sA[5] = {0.f, 0.f, 0.f, 0.f, 0.f}, qA[5] = {0.f, 0.f, 0.f, 0.f, 0.f};
  for (int t = blockIdx.x; t < ntiles; t += gridDim.x) {
    const int row0 = t * 64;
    const int grow = row0 + r;
    u16x8 lo = {0, 0, 0, 0, 0, 0, 0, 0}, hi = {0, 0, 0, 0, 0, 0, 0, 0};
    if (grow < N) {
      const float4* xp = reinterpret_cast<const float4*>(&X[(size_t)grow * 64 + q * 16]);
      float4 x0 = xp[0], x1 = xp[1], x2 = xp[2], x3 = xp[3];
      union { u16x8 v; unsigned int d[4]; } ul, uh;
      ul.d[0] = cvtpk(x0.x, x0.y); ul.d[1] = cvtpk(x0.z, x0.w);
      ul.d[2] = cvtpk(x1.x, x1.y); ul.d[3] = cvtpk(x1.z, x1.w);
      uh.d[0] = cvtpk(x2.x, x2.y); uh.d[1] = cvtpk(x2.z, x2.w);
      uh.d[2] = cvtpk(x3.x, x3.y); uh.d[3] = cvtpk(x3.z, x3.w);
      lo = ul.v; hi = uh.v;
      *(u16x8*)&Xb[(size_t)grow * 64 + q * 16] = lo;
      *(u16x8*)&Xb[(size_t)grow * 64 + q * 16 + 8] = hi;
    }
    __syncthreads();  // prev tile's At reads done
    char* wb = (char*)At + r * 128;
    *(u16x8*)(wb + ((q * 32) ^ sww)) = lo;
    *(u16x8*)(wb + ((q * 32 + 16) ^ sww)) = hi;
    __syncthreads();
#pragma unroll
    for (int rb = 0; rb < 4; ++rb) {
      const int rowa = rb * 16 + (l & 15);
      const char* ab = (const char*)At + rowa * 128;
      const int swa = (rowa & 7) << 4;
      const s16x8 a0 = *(const s16x8*)(ab + (kb ^ swa));
      const s16x8 a1 = *(const s16x8*)(ab + ((64 + kb) ^ swa));
#pragma unroll
      for (int i = 0; i < 5; ++i) {
        f32x4 acc = {0.f, 0.f, 0.f, 0.f};
        acc = mfma16(a0, wgt[i][0], acc);
        acc = mfma16(a1, wgt[i][1], acc);
        sA[i] += acc[0] + acc[1] + acc[2] + acc[3];
        qA[i] += acc[0] * acc[0] + acc[1] * acc[1] + acc[2] * acc[2] + acc[3] * acc[3];
      }
    }
  }
#pragma unroll
  for (int i = 0; i < 5; ++i) {
    float sp = sA[i], qp = qA[i];
    sp += __shfl_xor(sp, 16); sp += __shfl_xor(sp, 32);
    qp += __shfl_xor(qp, 16); qp += __shfl_xor(qp, 32);
    if (l < 16) {
      atomicAdd(&gsum[(w * 5 + i) * 16 + l], sp);
      atomicAdd(&gsq[(w * 5 + i) * 16 + l], qp);
    }
  }
}

// ---- K2: h1 = relu(a1*(Xb@W1)+c1) -> bf16; by-ct (wave=ct); multi-tile -----
__global__ __launch_bounds__(256) void kGemm1(const ushort* __restrict__ Xb,
                                              const ushort* __restrict__ WP,
                                              const float* __restrict__ sum1,
                                              const float* __restrict__ sq1,
                                              const float* __restrict__ g1,
                                              const float* __restrict__ b1,
                                              float invN, ushort* __restrict__ H1,
                                              int N, int ntiles) {
  __shared__ ushort At[64 * 64];
  __shared__ float a1s[64], c1s[64];
  const int tid = threadIdx.x;
  if (tid < 64) bnFin(sum1, sq1, g1, b1, invN, tid, a1s, c1s);
  const int l = tid & 63, w = tid >> 6;
  const int kb = (l >> 4) << 4;
  const int r = tid >> 2, q = tid & 3;
  const int sww = (r & 7) << 4;
  const u16x8* wp = (const u16x8*)WP;
  const s16x8 wg0 = (s16x8)wp[(w * 2 + 0) * 64 + l];
  const s16x8 wg1 = (s16x8)wp[(w * 2 + 1) * 64 + l];
  const int col = w * 16 + (l & 15);
  for (int t = blockIdx.x; t < ntiles; t += gridDim.x) {
    const int row0 = t * 64;
    const int grow = row0 + r;
    u16x8 lo = {0, 0, 0, 0, 0, 0, 0, 0}, hi = {0, 0, 0, 0, 0, 0, 0, 0};
    if (grow < N) {
      const u16x8* hp = (const u16x8*)&Xb[(size_t)grow * 64 + q * 16];
      lo = hp[0];
      hi = hp[1];
    }
    __syncthreads();
    char* wb = (char*)At + r * 128;
    *(u16x8*)(wb + ((q * 32) ^ sww)) = lo;
    *(u16x8*)(wb + ((q * 32 + 16) ^ sww)) = hi;
    __syncthreads();
    const float aj = a1s[col], cj = c1s[col];
#pragma unroll
    for (int rb = 0; rb < 4; ++rb) {
      const int rowa = rb * 16 + (l & 15);
      const char* ab = (const char*)At + rowa * 128;
      const int swa = (rowa & 7) << 4;
      const s16x8 a0 = *(const s16x8*)(ab + (kb ^ swa));
      const s16x8 a1 = *(const s16x8*)(ab + ((64 + kb) ^ swa));
      f32x4 acc = {0.f, 0.f, 0.f, 0.f};
      acc = mfma16(a0, wg0, acc);
      acc = mfma16(a1, wg1, acc);
#pragma unroll
      for (int reg = 0; reg < 4; ++reg) {
        const int gr = row0 + rb * 16 + ((l >> 4) << 2) + reg;
        if (gr < N)
          H1[(size_t)gr * 64 + col] =
              (ushort)cvtpk(fmaxf(fmaf(acc[reg], aj, cj), 0.f), 0.f);
      }
    }
  }
}

// ---- K3: Y2 = sum_k gather_k(h1) @ Wk[k] + BN2 stats -----------------------
// Direct-to-register gather in MFMA fragment layout: lane l needs exactly
// bytes [ks*16,+16) and [64+ks*16,+16) of H1 row src(w*16+(l&15)). No LDS,
// no barriers in the tile loop; all 18 loads per tile in flight at once.
__global__ __launch_bounds__(256) void kConv(const ushort* __restrict__ H1,
                                             const int* __restrict__ nbr,
                                             const ushort* __restrict__ WPk,
                                             ushort* __restrict__ Y2b,
                                             float* __restrict__ gsum,
                                             float* __restrict__ gsq,
                                             int N, int ntiles, int tpb) {
  __shared__ float lsum[64], lsq[64];
  const int tid = threadIdx.x;
  if (tid < 64) { lsum[tid] = 0.f; lsq[tid] = 0.f; }
  __syncthreads();
  const int l = tid & 63, w = tid >> 6;
  const int lr = l & 15;   // A row within wave tile
  const int ks = l >> 4;   // k-segment
  const u16x8* wp = (const u16x8*)WPk;
  float sAcc[4] = {0.f, 0.f, 0.f, 0.f}, qAcc[4] = {0.f, 0.f, 0.f, 0.f};
  const int t0 = blockIdx.x * tpb;
  const int t1 = (t0 + tpb < ntiles) ? (t0 + tpb) : ntiles;
  const s16x8 zf = {0, 0, 0, 0, 0, 0, 0, 0};
  for (int t = t0; t < t1; ++t) {
    const int row = t * 64 + w * 16 + lr;
    const bool valid = row < N;
    int srcs[9];
#pragma unroll
    for (int k = 0; k < 9; ++k)
      srcs[k] = valid ? nbr[(size_t)row * 9 + k] : -1;
    s16x8 A0[9], A1[9];
#pragma unroll
    for (int k = 0; k < 9; ++k) {
      const int sc = (srcs[k] < 0) ? 0 : srcs[k];
      const char* p = (const char*)H1 + (size_t)sc * 128 + ks * 16;
      A0[k] = *(const s16x8*)p;
      A1[k] = *(const s16x8*)(p + 64);
    }
#pragma unroll
    for (int k = 0; k < 9; ++k) {
      if (srcs[k] < 0) { A0[k] = zf; A1[k] = zf; }
    }
    f32x4 acc[4];
#pragma unroll
    for (int ct = 0; ct < 4; ++ct) acc[ct] = {0.f, 0.f, 0.f, 0.f};
    __builtin_amdgcn_s_setprio(1);
#pragma unroll
    for (int k = 0; k < 9; ++k) {
#pragma unroll
      for (int ct = 0; ct < 4; ++ct) {
        s16x8 b0 = (s16x8)wp[(size_t)((k * 4 + ct) * 2 + 0) * 64 + l];
        s16x8 b1 = (s16x8)wp[(size_t)((k * 4 + ct) * 2 + 1) * 64 + l];
        acc[ct] = mfma16(A0[k], b0, acc[ct]);
        acc[ct] = mfma16(A1[k], b1, acc[ct]);
      }
    }
    __builtin_amdgcn_s_setprio(0);
#pragma unroll
    for (int ct = 0; ct < 4; ++ct) {
      const f32x4 v = acc[ct];
      const int col = ct * 16 + (l & 15);
#pragma unroll
      for (int reg = 0; reg < 4; ++reg) {
        const int gr = t * 64 + w * 16 + (ks << 2) + reg;
        if (gr < N) Y2b[(size_t)gr * 64 + col] = (ushort)cvtpk(v[reg], v[reg]);
      }
      sAcc[ct] += v[0] + v[1] + v[2] + v[3];
      qAcc[ct] += v[0] * v[0] + v[1] * v[1] + v[2] * v[2] + v[3] * v[3];
    }
  }
#pragma unroll
  for (int ct = 0; ct < 4; ++ct) {
    float sp = sAcc[ct], qp = qAcc[ct];
    sp += __shfl_xor(sp, 16); sp += __shfl_xor(sp, 32);
    qp += __shfl_xor(qp, 16); qp += __shfl_xor(qp, 32);
    if (l < 16) {
      atomicAdd(&lsum[ct * 16 + l], sp);
      atomicAdd(&lsq[ct * 16 + l], qp);
    }
  }
  __syncthreads();
  if (tid < 64) {
    atomicAdd(&gsum[tid], lsum[tid]);
    atomicAdd(&gsq[tid], lsq[tid]);
  }
}

// ---- K4: BN3 stats of h2@W3 (h2 in-register); by-ct waves; multi-tile ------
__global__ __launch_bounds__(256) void kH2S3(const ushort* __restrict__ Y2b,
                                             const float* __restrict__ sum2,
                                             const float* __restrict__ sq2,
                                             const float* __restrict__ g2,
                                             const float* __restrict__ b2,
                                             float invN,
                                             const ushort* __restrict__ WP3,
                                             float* __restrict__ gsum,
                                             float* __restrict__ gsq,
                                             int N, int ntiles) {
  __shared__ ushort At[64 * 64];
  __shared__ float a2s[64], c2s[64];
  const int tid = threadIdx.x;
  if (tid < 64) bnFin(sum2, sq2, g2, b2, invN, tid, a2s, c2s);
  const int l = tid & 63, w = tid >> 6;
  const int kb = (l >> 4) << 4;
  const int r = tid >> 2, q = tid & 3;
  const int sww = (r & 7) << 4;
  const u16x8* wp = (const u16x8*)WP3;
  s16x8 wgt[4][2];
#pragma unroll
  for (int i = 0; i < 4; ++i)
#pragma unroll
    for (int j = 0; j < 2; ++j) wgt[i][j] = (s16x8)wp[((w * 4 + i) * 2 + j) * 64 + l];
  float sA[4] = {0.f, 0.f, 0.f, 0.f}, qA[4] = {0.f, 0.f, 0.f, 0.f};
  __syncthreads();  // a2s ready
  for (int t = blockIdx.x; t < ntiles; t += gridDim.x) {
    const int row0 = t * 64;
    const int grow = row0 + r;
    u16x8 lo = {0, 0, 0, 0, 0, 0, 0, 0}, hi = {0, 0, 0, 0, 0, 0, 0, 0};
    if (grow < N) {
      const u16x8* yp = (const u16x8*)&Y2b[(size_t)grow * 64 + q * 16];
      u16x8 ylo = yp[0], yhi = yp[1];
      const int cb = q * 16;
      float f[8], g[8];
#pragma unroll
      for (int i = 0; i < 8; ++i) {
        f[i] = fmaxf(fmaf(bf2f(ylo[i]), a2s[cb + i], c2s[cb + i]), 0.f);
        g[i] = fmaxf(fmaf(bf2f(yhi[i]), a2s[cb + 8 + i], c2s[cb + 8 + i]), 0.f);
      }
      union { u16x8 v; unsigned int d[4]; } ul, uh;
#pragma unroll
      for (int i = 0; i < 4; ++i) {
        ul.d[i] = cvtpk(f[2 * i], f[2 * i + 1]);
        uh.d[i] = cvtpk(g[2 * i], g[2 * i + 1]);
      }
      lo = ul.v; hi = uh.v;
    }
    __syncthreads();  // prev reads done
    char* wb = (char*)At + r * 128;
    *(u16x8*)(wb + ((q * 32) ^ sww)) = lo;
    *(u16x8*)(wb + ((q * 32 + 16) ^ sww)) = hi;
    __syncthreads();
#pragma unroll
    for (int rb = 0; rb < 4; ++rb) {
      const int rowa = rb * 16 + (l & 15);
      const char* ab = (const char*)At + rowa * 128;
      const int swa = (rowa & 7) << 4;
      const s16x8 a0 = *(const s16x8*)(ab + (kb ^ swa));
      const s16x8 a1 = *(const s16x8*)(ab + ((64 + kb) ^ swa));
#pragma unroll
      for (int i = 0; i < 4; ++i) {
        f32x4 acc = {0.f, 0.f, 0.f, 0.f};
        acc = mfma16(a0, wgt[i][0], acc);
        acc = mfma16(a1, wgt[i][1], acc);
        sA[i] += acc[0] + acc[1] + acc[2] + acc[3];
        qA[i] += acc[0] * acc[0] + acc[1] * acc[1] + acc[2] * acc[2] + acc[3] * acc[3];
      }
    }
  }
#pragma unroll
  for (int i = 0; i < 4; ++i) {
    float sp = sA[i], qp = qA[i];
    sp += __shfl_xor(sp, 16); sp += __shfl_xor(sp, 32);
    qp += __shfl_xor(qp, 16); qp += __shfl_xor(qp, 32);
    if (l < 16) {
      atomicAdd(&gsum[(w * 4 + i) * 16 + l], sp);
      atomicAdd(&gsq[(w * 4 + i) * 16 + l], qp);
    }
  }
}

// ---- K5: out = relu(a3*(h2@W3) + aS*(Xb@Ws) + c3+cS); by-ct; multi-tile ----
__global__ __launch_bounds__(256, 2) void kFinal(
    const ushort* __restrict__ Y2b, const ushort* __restrict__ Xb,
    const ushort* __restrict__ WP3, const ushort* __restrict__ WP1S,
    const float* __restrict__ sum2, const float* __restrict__ sq2,
    const float* __restrict__ g2, const float* __restrict__ b2,
    const float* __restrict__ sum3, const float* __restrict__ sq3,
    const float* __restrict__ g3, const float* __restrict__ b3,
    const float* __restrict__ sumS, const float* __restrict__ sqS,
    const float* __restrict__ gs, const float* __restrict__ bs,
    float invN, float* __restrict__ OUT, int N, int ntiles) {
  __shared__ ushort Ah[64 * 64];
  __shared__ ushort Ax[64 * 64];
  __shared__ float a2s[64], c2s[64];
  __shared__ float a3s[256], c3s[256], aSs[256], cSs[256];
  const int tid = threadIdx.x;
  if (tid < 64) bnFin(sum2, sq2, g2, b2, invN, tid, a2s, c2s);
  bnFin(sum3, sq3, g3, b3, invN, tid, a3s, c3s);
  bnFin(sumS, sqS, gs, bs, invN, tid, aSs, cSs);
  const int l = tid & 63, w = tid >> 6;
  const int kb = (l >> 4) << 4;
  const int r = tid >> 2, q = tid & 3;
  const int sww = (r & 7) << 4;
  const u16x8* wp3 = (const u16x8*)WP3;
  const u16x8* wps = (const u16x8*)WP1S + 8 * 64;  // skip W1's 4 ct
  s16x8 w3[4][2], wsv[4][2];
#pragma unroll
  for (int i = 0; i < 4; ++i)
#pragma unroll
    for (int j = 0; j < 2; ++j) {
      w3[i][j]  = (s16x8)wp3[((w * 4 + i) * 2 + j) * 64 + l];
      wsv[i][j] = (s16x8)wps[((w * 4 + i) * 2 + j) * 64 + l];
    }
  __syncthreads();  // BN LDS ready
  for (int t = blockIdx.x; t < ntiles; t += gridDim.x) {
    const int row0 = t * 64;
    const int grow = row0 + r;
    u16x8 xlo = {0, 0, 0, 0, 0, 0, 0, 0}, xhi = {0, 0, 0, 0, 0, 0, 0, 0};
    u16x8 hlo = {0, 0, 0, 0, 0, 0, 0, 0}, hhi = {0, 0, 0, 0, 0, 0, 0, 0};
    if (grow < N) {
      const u16x8* hp = (const u16x8*)&Xb[(size_t)grow * 64 + q * 16];
      xlo = hp[0];
      xhi = hp[1];
      const u16x8* yp = (const u16x8*)&Y2b[(size_t)grow * 64 + q * 16];
      u16x8 ylo = yp[0], yhi = yp[1];
      const int cb = q * 16;
      float f[8], g[8];
#pragma unroll
      for (int i = 0; i < 8; ++i) {
        f[i] = fmaxf(fmaf(bf2f(ylo[i]), a2s[cb + i], c2s[cb + i]), 0.f);
        g[i] = fmaxf(fmaf(bf2f(yhi[i]), a2s[cb + 8 + i], c2s[cb + 8 + i]), 0.f);
      }
      union { u16x8 v; unsigned int d[4]; } ul, uh;
#pragma unroll
      for (int i = 0; i < 4; ++i) {
        ul.d[i] = cvtpk(f[2 * i], f[2 * i + 1]);
        uh.d[i] = cvtpk(g[2 * i], g[2 * i + 1]);
      }
      hlo = ul.v; hhi = uh.v;
    }
    __syncthreads();  // prev reads done
    {
      char* bh = (char*)Ah + r * 128;
      char* bx = (char*)Ax + r * 128;
      *(u16x8*)(bh + ((q * 32) ^ sww)) = hlo;
      *(u16x8*)(bh + ((q * 32 + 16) ^ sww)) = hhi;
      *(u16x8*)(bx + ((q * 32) ^ sww)) = xlo;
      *(u16x8*)(bx + ((q * 32 + 16) ^ sww)) = xhi;
    }
    __syncthreads();
    // hoist A fragments (16 ds_reads), then 64 MFMAs with zero LDS
    s16x8 ah0[4], ah1[4], ax0[4], ax1[4];
#pragma unroll
    for (int rb = 0; rb < 4; ++rb) {
      const int rowa = rb * 16 + (l & 15);
      const int swa = (rowa & 7) << 4;
      const char* hb = (const char*)Ah + rowa * 128;
      const char* xb2 = (const char*)Ax + rowa * 128;
      ah0[rb] = *(const s16x8*)(hb + (kb ^ swa));
      ah1[rb] = *(const s16x8*)(hb + ((64 + kb) ^ swa));
      ax0[rb] = *(const s16x8*)(xb2 + (kb ^ swa));
      ax1[rb] = *(const s16x8*)(xb2 + ((64 + kb) ^ swa));
    }
#pragma unroll
    for (int i = 0; i < 4; ++i) {
      const int col = (w * 4 + i) * 16 + (l & 15);
      const float a3j = a3s[col], aSj = aSs[col];
      const float ccj = c3s[col] + cSs[col];
#pragma unroll
      for (int rb = 0; rb < 4; ++rb) {
        f32x4 acc3 = {0.f, 0.f, 0.f, 0.f};
        acc3 = mfma16(ah0[rb], w3[i][0], acc3);
        acc3 = mfma16(ah1[rb], w3[i][1], acc3);
        f32x4 accS = {0.f, 0.f, 0.f, 0.f};
        accS = mfma16(ax0[rb], wsv[i][0], accS);
        accS = mfma16(ax1[rb], wsv[i][1], accS);
#pragma unroll
        for (int reg = 0; reg < 4; ++reg) {
          const int gr = row0 + rb * 16 + ((l >> 4) << 2) + reg;
          if (gr < N) {
            const float ov = fmaxf(fmaf(acc3[reg], a3j, fmaf(accS[reg], aSj, ccj)), 0.f);
            __builtin_nontemporal_store(ov, &OUT[(size_t)gr * 256 + col]);
          }
        }
      }
    }
  }
}

extern "C" void kernel_launch(void* const* d_in, const int* in_sizes, int n_in,
                              void* d_out, int out_size, void* d_ws, size_t ws_size,
                              hipStream_t stream) {
  const float* X  = (const float*)d_in[0];
  const int*   nbr = (const int*)d_in[1];
  const float* W1 = (const float*)d_in[2];
  const float* g1 = (const float*)d_in[3];
  const float* b1 = (const float*)d_in[4];
  const float* Wk = (const float*)d_in[5];
  const float* g2 = (const float*)d_in[6];
  const float* b2 = (const float*)d_in[7];
  const float* W3 = (const float*)d_in[8];
  const float* g3 = (const float*)d_in[9];
  const float* b3 = (const float*)d_in[10];
  const float* Ws = (const float*)d_in[11];
  const float* gs = (const float*)d_in[12];
  const float* bs = (const float*)d_in[13];
  float* out = (float*)d_out;
  float* ws  = (float*)d_ws;

  const int N = in_sizes[0] / 64;
  const float invN = 1.f / (float)N;
  const int ntiles = (N + 63) / 64;

  // ws layout (float offsets)
  float* sum1S = ws + 0;     // [320]
  float* sq1S  = ws + 320;   // [320]
  float* sum2  = ws + 640;   // [64]
  float* sq2   = ws + 704;   // [64]
  float* sum3  = ws + 768;   // [256]
  float* sq3   = ws + 1024;  // [256]
  ushort* WP1S = (ushort*)(ws + 1280);   // 20480 bf16
  ushort* WPkP = (ushort*)(ws + 11520);  // 36864 bf16
  ushort* WP3P = (ushort*)(ws + 29952);  // 16384 bf16
  ushort* Xb   = (ushort*)(ws + 38144);                      // N*64 bf16
  ushort* Y2b  = (ushort*)(ws + 38144 + (size_t)N * 32);     // N*64 bf16
  ushort* H1b  = (ushort*)(ws + 38144 + (size_t)N * 64);     // N*64 bf16

  const int convGrid = 1024;
  const int tpb = (ntiles + convGrid - 1) / convGrid;

  kPackW<<<288, 256, 0, stream>>>(W1, Ws, Wk, W3, WP1S, WPkP, WP3P, ws);
  kStatsXW<<<508, 256, 0, stream>>>(X, WP1S, Xb, sum1S, sq1S, N, ntiles);
  kGemm1<<<508, 256, 0, stream>>>(Xb, WP1S, sum1S, sq1S, g1, b1, invN, H1b, N, ntiles);
  kConv<<<convGrid, 256, 0, stream>>>(H1b, nbr, WPkP, Y2b, sum2, sq2, N, ntiles, tpb);
  kH2S3<<<508, 256, 0, stream>>>(Y2b, sum2, sq2, g2, b2, invN, WP3P, sum3, sq3, N, ntiles);
  kFinal<<<512, 256, 0, stream>>>(Y2b, Xb, WP3P, WP1S, sum2, sq2, g2, b2,
                                  sum3, sq3, g3, b3, sum1S + 64, sq1S + 64,
                                  gs, bs, invN, out, N, ntiles);
}